// Round 11
// baseline (177.889 us; speedup 1.0000x reference)
//
#include <hip/hip_runtime.h>
#include <hip/hip_bf16.h>

// DCNv2 inception, R20: explicit 2-deep GATHER pipeline per wave.
// Ledger: R13 ordering NULL, R15 cap-release NULL, R16 LDS-occupancy NULL,
// R18 direct-L2 negative, R19 param-LDS NULL. Surviving fact: per wave-tap
// ~10K cyc vs ~600-cyc chain; VALUBusy 34% at 4 waves/SIMD = 8.5% per-wave
// duty; co-resident waves stall TOGETHER -> within-wave ILP=1 is the one
// untested structural lever (R14 never ran: (512,4) capped regs at 64 and
// spilled 1.4GB). R20 fixes R14's two bugs: prefetch ONLY gathers+params
// of tap k+1 (named regs, ~39 extra live), NOT B-frags; and (512,2) so
// regalloc may use up to 128 -- free, since the 65KB window pins 2
// blocks/CU regardless (4 waves/SIMD x 128 = full file). Params move to
// distance-4 (global, ping-pong); prep is 1 tap ahead of consume; oow
// fixup deferred to consume (rare). Window/bilinear/MFMA/epilogue = R13b.

typedef __attribute__((ext_vector_type(8))) short bf16x8;
typedef __attribute__((ext_vector_type(8))) unsigned short u16x8;
typedef __attribute__((ext_vector_type(4))) unsigned u32x4;
typedef __attribute__((ext_vector_type(4))) float f32x4;
typedef __attribute__((ext_vector_type(2))) float f32x2;

#define WR 16    // window rows
#define WC 30    // window cols
#define WS 68    // window position stride in shorts (34 dwords -> +2 bank rotate)
#define SLS 20   // slab o-stride in floats

__device__ __forceinline__ unsigned short f2bf(float f) {
    __hip_bfloat16 h = __float2bfloat16(f);
    return *reinterpret_cast<unsigned short*>(&h);
}
__device__ __forceinline__ f32x2 unpk(unsigned u) {
    f32x2 r;
    r[0] = __uint_as_float(u << 16);
    r[1] = __uint_as_float(u & 0xffff0000u);
    return r;
}

// Merged prep: blocks [0,256): x[b][c][h][w] f32 -> xTb[b][h][w][c] bf16;
// blocks [256,1584): f[o][c][k] f32 -> wpF in MFMA-fragment order:
//   wpF[k][ct][cg][lane][j] = f[o=ct*16+(lane&15)][c=cg*32+(lane>>4)*8+j][k]
__global__ __launch_bounds__(256) void k_prep(
    const float* __restrict__ x,
    const float* __restrict__ f1, const float* __restrict__ f2, const float* __restrict__ f3,
    unsigned short* __restrict__ xTb,
    unsigned short* __restrict__ wp1, unsigned short* __restrict__ wp2, unsigned short* __restrict__ wp3) {
    __shared__ float tile[64][65];
    int bid = blockIdx.x;
    int tid = threadIdx.x;
    if (bid < 256) {
        int b = bid >> 6, h = bid & 63;
        {
            int w = tid & 63, c4 = tid >> 6;
            const float* xp = x + (((b * 64) * 64 + h) * 64) + w;
            #pragma unroll
            for (int i = 0; i < 16; ++i) {
                int c = c4 * 16 + i;
                tile[c][w] = xp[c * 4096];
            }
        }
        __syncthreads();
        {
            int c = tid & 63, w4 = tid >> 6;
            unsigned short* op = xTb + (((b * 64 + h) * 64) * 64) + c;
            #pragma unroll
            for (int i = 0; i < 16; ++i) {
                int ww = w4 * 16 + i;
                op[ww * 64] = f2bf(tile[c][ww]);
            }
        }
    } else {
        int idx = (bid - 256) * 256 + tid;      // 83*4096 = 339968 total
        const float* f; unsigned short* wp; int K, rel;
        if (idx < 36864)       { f = f1; wp = wp1; K = 9;  rel = idx; }
        else if (idx < 139264) { f = f2; wp = wp2; K = 25; rel = idx - 36864; }
        else                   { f = f3; wp = wp3; K = 49; rel = idx - 139264; }
        int k    = rel >> 12;
        int r2   = rel & 4095;
        int ct   = r2 >> 10;
        int cg   = (r2 >> 9) & 1;
        int lane = (r2 >> 3) & 63;
        int j    = r2 & 7;
        int o = ct * 16 + (lane & 15);
        int c = cg * 32 + (lane >> 4) * 8 + j;
        wp[rel] = f2bf(f[(o * 64 + c) * K + k]);
    }
}

// PREP: weights + oow flag + 8 window ds_reads for one tap -> suffixed regs.
// Junk-safe: clamped window addresses, so a redundant final prep is harmless.
#define PREP(S, dyp, dxp, mkp)                                                \
    {                                                                         \
        float py = (float)(h - pad + kyP) + (dyp);                            \
        float px = (float)(pw - pad + kxP) + (dxp);                           \
        float y0f = floorf(py), x0f = floorf(px);                             \
        float wy = py - y0f, wx = px - x0f;                                   \
        int y0 = (int)y0f, x0 = (int)x0f;                                     \
        int y1 = y0 + 1, x1 = x0 + 1;                                         \
        float fy0 = ((unsigned)y0 < 64u) ? (1.f - wy) * (mkp) : 0.f;          \
        float fy1 = ((unsigned)y1 < 64u) ? wy * (mkp)         : 0.f;          \
        float gx0 = ((unsigned)x0 < 64u) ? (1.f - wx)         : 0.f;          \
        float gx1 = ((unsigned)x1 < 64u) ? wx                 : 0.f;          \
        w00##S = fy0 * gx0; w01##S = fy0 * gx1;                               \
        w10##S = fy1 * gx0; w11##S = fy1 * gx1;                               \
        int r0 = y0 - ylo, r1 = r0 + 1;                                       \
        int c0 = x0 - cxlo, c1 = c0 + 1;                                      \
        oow##S = ((w00##S != 0.f) & (((unsigned)r0 >= WR) | ((unsigned)c0 >= WC)))  \
               | ((w01##S != 0.f) & (((unsigned)r0 >= WR) | ((unsigned)c1 >= WC)))  \
               | ((w10##S != 0.f) & (((unsigned)r1 >= WR) | ((unsigned)c0 >= WC)))  \
               | ((w11##S != 0.f) & (((unsigned)r1 >= WR) | ((unsigned)c1 >= WC))); \
        y0s##S = y0; x0s##S = x0;                                             \
        int r0c = min(max(r0, 0), WR - 1), r1c = min(max(r1, 0), WR - 1);     \
        int c0c = min(max(c0, 0), WC - 1), c1c = min(max(c1, 0), WC - 1);     \
        int p00 = (r0c * WC + c0c) * WS;                                      \
        int p01 = (r0c * WC + c1c) * WS;                                      \
        int p10 = (r1c * WC + c0c) * WS;                                      \
        int p11 = (r1c * WC + c1c) * WS;                                      \
        g00a##S = *(const u32x4*)(win + p00 + ch0);                           \
        g01a##S = *(const u32x4*)(win + p01 + ch0);                           \
        g10a##S = *(const u32x4*)(win + p10 + ch0);                           \
        g11a##S = *(const u32x4*)(win + p11 + ch0);                           \
        g00b##S = *(const u32x4*)(win + p00 + 32 + ch0);                      \
        g01b##S = *(const u32x4*)(win + p01 + 32 + ch0);                      \
        g10b##S = *(const u32x4*)(win + p10 + 32 + ch0);                      \
        g11b##S = *(const u32x4*)(win + p11 + 32 + ch0);                      \
        if (++kxP == kw) { kxP = 0; ++kyP; }                                  \
    }

// CONSUME: B-frag loads, rare oow fixup, bilinear+pack, 8 MFMA for tap kk.
#define CONSUME(S, kk)                                                        \
    {                                                                         \
        const unsigned short* wpk = wpF + ((kk) << 12) + lofs;                \
        bf16x8 b00 = *(const bf16x8*)(wpk);                                   \
        bf16x8 b01 = *(const bf16x8*)(wpk + 512);                             \
        bf16x8 b10 = *(const bf16x8*)(wpk + 1024);                            \
        bf16x8 b11 = *(const bf16x8*)(wpk + 1536);                            \
        bf16x8 b20 = *(const bf16x8*)(wpk + 2048);                            \
        bf16x8 b21 = *(const bf16x8*)(wpk + 2560);                            \
        bf16x8 b30 = *(const bf16x8*)(wpk + 3072);                            \
        bf16x8 b31 = *(const bf16x8*)(wpk + 3584);                            \
        if (oow##S) {                                                         \
            int y0g = min(max(y0s##S, 0), 63), y1g = min(max(y0s##S + 1, 0), 63); \
            int x0g = min(max(x0s##S, 0), 63), x1g = min(max(x0s##S + 1, 0), 63); \
            int o00 = ((y0g << 6) + x0g) << 6;                                \
            int o01 = ((y0g << 6) + x1g) << 6;                                \
            int o10 = ((y1g << 6) + x0g) << 6;                                \
            int o11 = ((y1g << 6) + x1g) << 6;                                \
            g00a##S = *(const u32x4*)(xb + o00 + ch0);                        \
            g01a##S = *(const u32x4*)(xb + o01 + ch0);                        \
            g10a##S = *(const u32x4*)(xb + o10 + ch0);                        \
            g11a##S = *(const u32x4*)(xb + o11 + ch0);                        \
            g00b##S = *(const u32x4*)(xb + o00 + 32 + ch0);                   \
            g01b##S = *(const u32x4*)(xb + o01 + 32 + ch0);                   \
            g10b##S = *(const u32x4*)(xb + o10 + 32 + ch0);                   \
            g11b##S = *(const u32x4*)(xb + o11 + 32 + ch0);                   \
        }                                                                     \
        f32x2 W00 = {w00##S, w00##S}, W01 = {w01##S, w01##S};                 \
        f32x2 W10 = {w10##S, w10##S}, W11 = {w11##S, w11##S};                 \
        union { bf16x8 v; unsigned short u[8]; } A0, A1;                      \
        _Pragma("unroll")                                                     \
        for (int j2 = 0; j2 < 4; ++j2) {                                      \
            f32x2 s0 = W00 * unpk(g00a##S[j2]) + W01 * unpk(g01a##S[j2])      \
                     + W10 * unpk(g10a##S[j2]) + W11 * unpk(g11a##S[j2]);     \
            f32x2 s1 = W00 * unpk(g00b##S[j2]) + W01 * unpk(g01b##S[j2])      \
                     + W10 * unpk(g10b##S[j2]) + W11 * unpk(g11b##S[j2]);     \
            A0.u[2 * j2]     = f2bf(s0[0]);                                   \
            A0.u[2 * j2 + 1] = f2bf(s0[1]);                                   \
            A1.u[2 * j2]     = f2bf(s1[0]);                                   \
            A1.u[2 * j2 + 1] = f2bf(s1[1]);                                   \
        }                                                                     \
        acc[0] = __builtin_amdgcn_mfma_f32_16x16x32_bf16(A0.v, b00, acc[0], 0, 0, 0); \
        acc[0] = __builtin_amdgcn_mfma_f32_16x16x32_bf16(A1.v, b01, acc[0], 0, 0, 0); \
        acc[1] = __builtin_amdgcn_mfma_f32_16x16x32_bf16(A0.v, b10, acc[1], 0, 0, 0); \
        acc[1] = __builtin_amdgcn_mfma_f32_16x16x32_bf16(A1.v, b11, acc[1], 0, 0, 0); \
        acc[2] = __builtin_amdgcn_mfma_f32_16x16x32_bf16(A0.v, b20, acc[2], 0, 0, 0); \
        acc[2] = __builtin_amdgcn_mfma_f32_16x16x32_bf16(A1.v, b21, acc[2], 0, 0, 0); \
        acc[3] = __builtin_amdgcn_mfma_f32_16x16x32_bf16(A0.v, b30, acc[3], 0, 0, 0); \
        acc[3] = __builtin_amdgcn_mfma_f32_16x16x32_bf16(A1.v, b31, acc[3], 0, 0, 0); \
    }

#define ROTATE(kq)                                                            \
    {                                                                         \
        int kn = min((kq), ke - 1);                                           \
        float dyN = offp[kn * 8192];                                          \
        float dxN = offp[kn * 8192 + 4096];                                   \
        float mkN = mskp[kn * 4096];                                          \
        dyA = dyB; dyB = dyC; dyC = dyN;                                      \
        dxA = dxB; dxB = dxC; dxC = dxN;                                      \
        mkA = mkB; mkB = mkC; mkC = mkN;                                      \
    }

__global__ __launch_bounds__(512, 2) void k_dcn(
    const unsigned short* __restrict__ xTb,
    const float* __restrict__ off1, const float* __restrict__ msk1, const unsigned short* __restrict__ wp1,
    const float* __restrict__ off2, const float* __restrict__ msk2, const unsigned short* __restrict__ wp2,
    const float* __restrict__ off3, const float* __restrict__ msk3, const unsigned short* __restrict__ wp3,
    float* __restrict__ out) {

    __shared__ __align__(16) unsigned char smem[WR * WC * WS * 2];   // 65,280 B
    unsigned short* win = (unsigned short*)smem;
    float* slab = (float*)smem;          // aliased after taps (8*1280*4 = 40,960 B)

    int tile = blockIdx.x;               // 0..1023
    int b  = tile >> 8;
    int h  = (tile >> 2) & 63;
    int w0 = (tile & 3) << 4;

    int tid  = threadIdx.x;
    int wv   = tid >> 6;                 // 0..7
    int lane = tid & 63;
    int quad = lane >> 4;
    int l16  = lane & 15;
    int ylo  = h - 7, cxlo = w0 - 7;

    const unsigned short* xb = xTb + ((size_t)b << 18);

    int pw   = w0 + l16;
    int ch0  = quad << 3;
    int lofs = lane << 3;                // lane*8 shorts = lane*16 B

    // ---- per-wave descriptor (scalar, compact): 8 single tap-ranges ----
    const float* offs; const float* msks; const unsigned short* wpF;
    int ks, ke, kw, pad;
    switch (wv) {
        case 0:  offs = off1; msks = msk1; wpF = wp1; kw = 3; pad = 1; ks = 0;  ke = 9;  break;
        case 1:  offs = off2; msks = msk2; wpF = wp2; kw = 5; pad = 2; ks = 0;  ke = 12; break;
        case 2:  offs = off2; msks = msk2; wpF = wp2; kw = 5; pad = 2; ks = 12; ke = 25; break;
        case 3:  offs = off3; msks = msk3; wpF = wp3; kw = 7; pad = 3; ks = 0;  ke = 10; break;
        case 4:  offs = off3; msks = msk3; wpF = wp3; kw = 7; pad = 3; ks = 10; ke = 20; break;
        case 5:  offs = off3; msks = msk3; wpF = wp3; kw = 7; pad = 3; ks = 20; ke = 30; break;
        case 6:  offs = off3; msks = msk3; wpF = wp3; kw = 7; pad = 3; ks = 30; ke = 40; break;
        default: offs = off3; msks = msk3; wpF = wp3; kw = 7; pad = 3; ks = 40; ke = 49; break;
    }
    int K2 = (kw == 3) ? 9 : (kw == 5) ? 25 : 49;
    const float* offp = offs + ((b * 2 * K2) * 4096) + (h << 6) + pw;  // +k*8192 dy, +4096 dx
    const float* mskp = msks + ((b * K2) * 4096) + (h << 6) + pw;      // +k*4096

    // ---- param preload, 3 slots, before staging (HBM latency hides) ----
    int kp1 = min(ks + 1, ke - 1), kp2 = min(ks + 2, ke - 1);
    float dyA = offp[ks * 8192], dxA = offp[ks * 8192 + 4096], mkA = mskp[ks * 4096];
    float dyB = offp[kp1 * 8192], dxB = offp[kp1 * 8192 + 4096], mkB = mskp[kp1 * 4096];
    float dyC = offp[kp2 * 8192], dxC = offp[kp2 * 8192 + 4096], mkC = mskp[kp2 * 4096];

    // ---- stage window: 480 positions x 128 B, coalesced, 512 threads ----
    {
        int j = tid & 7;
        for (int p = tid >> 3; p < WR * WC; p += 64) {
            int r = p / WC, cc = p - r * WC;
            int y = min(max(ylo + r, 0), 63);
            int x = min(max(cxlo + cc, 0), 63);
            *(u16x8*)(win + p * WS + j * 8) =
                *(const u16x8*)(xb + (((y << 6) + x) << 6) + j * 8);
        }
    }
    __syncthreads();

    f32x4 acc[4];
    #pragma unroll
    for (int i = 0; i < 4; ++i) acc[i] = (f32x4){0.f, 0.f, 0.f, 0.f};

    int kyP = ks / kw, kxP = ks - (ks / kw) * kw;   // coords of next tap to PREP

    // pipeline registers (named; two stages P and Q)
    float w00P, w01P, w10P, w11P, w00Q, w01Q, w10Q, w11Q;
    int   oowP, y0sP, x0sP, oowQ, y0sQ, x0sQ;
    u32x4 g00aP, g01aP, g10aP, g11aP, g00bP, g01bP, g10bP, g11bP;
    u32x4 g00aQ, g01aQ, g10aQ, g11aQ, g00bQ, g01bQ, g10bQ, g11bQ;

    // prologue: prep tap ks into P (uses dyA = params(ks)), then rotate
    PREP(P, dyA, dxA, mkA)
    ROTATE(ks + 3)                      // dyA now = params(ks+1)

    int k = ks;
    for (;;) {
        // phase A: prep k+1 -> Q (dyA = params(k+1)); consume k <- P
        PREP(Q, dyA, dxA, mkA)
        ROTATE(k + 4)
        CONSUME(P, k)
        ++k;
        if (k >= ke) break;
        // phase B: prep k+1 -> P ; consume k <- Q
        PREP(P, dyA, dxA, mkA)
        ROTATE(k + 4)
        CONSUME(Q, k)
        ++k;
        if (k >= ke) break;
    }

    __syncthreads();    // all waves done reading window; safe to alias as slab

    #pragma unroll
    for (int ct = 0; ct < 4; ++ct) {
        *(f32x4*)&slab[wv * 1280 + (ct * 16 + l16) * SLS + quad * 4] = acc[ct];
    }
    __syncthreads();

    // in-block reduce + store: 768 items = 192 o x 4 groups of 4 px
    // br0 (o<64): slab 0; br1: slabs 1+2; br2: slabs 3..7
    for (int it = tid; it < 768; it += 512) {
        int g = it & 3;
        int o = it >> 2;            // 0..191 (concat order br0|br1|br2)
        int oo = o & 63;
        int base = oo * SLS + g * 4;
        f32x4 v;
        if (o < 64) {
            v = *(const f32x4*)&slab[base];
        } else if (o < 128) {
            f32x4 a0 = *(const f32x4*)&slab[1 * 1280 + base];
            f32x4 a1 = *(const f32x4*)&slab[2 * 1280 + base];
            #pragma unroll
            for (int r = 0; r < 4; ++r) v[r] = a0[r] + a1[r];
        } else {
            f32x4 a0 = *(const f32x4*)&slab[3 * 1280 + base];
            f32x4 a1 = *(const f32x4*)&slab[4 * 1280 + base];
            f32x4 a2 = *(const f32x4*)&slab[5 * 1280 + base];
            f32x4 a3 = *(const f32x4*)&slab[6 * 1280 + base];
            f32x4 a4 = *(const f32x4*)&slab[7 * 1280 + base];
            #pragma unroll
            for (int r = 0; r < 4; ++r) v[r] = (a0[r] + a1[r]) + (a2[r] + a3[r]) + a4[r];
        }
        *(f32x4*)&out[(((size_t)b * 192 + o) * 64 + h) * 64 + w0 + g * 4] = v;
    }
}

extern "C" void kernel_launch(void* const* d_in, const int* in_sizes, int n_in,
                              void* d_out, int out_size, void* d_ws, size_t ws_size,
                              hipStream_t stream) {
    const float* x    = (const float*)d_in[0];
    const float* f1   = (const float*)d_in[1];
    const float* off1 = (const float*)d_in[2];
    const float* msk1 = (const float*)d_in[3];
    const float* f2   = (const float*)d_in[4];
    const float* off2 = (const float*)d_in[5];
    const float* msk2 = (const float*)d_in[6];
    const float* f3   = (const float*)d_in[7];
    const float* off3 = (const float*)d_in[8];
    const float* msk3 = (const float*)d_in[9];
    float* out = (float*)d_out;

    // ws: xTb 2MB bf16 | wpF1/wpF2/wpF3 bf16 (fragment-major)
    unsigned short* xTb = (unsigned short*)d_ws;
    unsigned short* wp1 = xTb + 4 * 64 * 64 * 64;
    unsigned short* wp2 = wp1 + 9 * 4096;
    unsigned short* wp3 = wp2 + 25 * 4096;

    k_prep<<<dim3(1584), dim3(256), 0, stream>>>(x, f1, f2, f3, xTb, wp1, wp2, wp3);
    k_dcn<<<dim3(1024), dim3(512), 0, stream>>>(xTb,
                                                off1, msk1, wp1,
                                                off2, msk2, wp2,
                                                off3, msk3, wp3,
                                                out);
}

// Round 12
// 170.942 us; speedup vs baseline: 1.0406x; 1.0406x over previous
//
#include <hip/hip_runtime.h>
#include <hip/hip_bf16.h>

// DCNv2 inception, R21: 4x8 tile, 32 px/wave -- halve tap-iterations.
// Ledger of falsified mechanisms (all ±10% of 91.5us): R13 ordering NULL,
// R14/R20 ILP-2 NEGATIVE, R15 reg-cap NULL, R16 blocks/CU NULL, R18
// direct-L2 NEGATIVE, R19 param-LDS NULL. Invariant: ~2,650 cy per
// tap-ITERATION per SIMD regardless of chain contents -> cost is
// per-iteration, not per-op. R21 is the one untouched lever: amortize.
// Tile 4x8 = 32 px/wave (2 A-fragment sets): same 8 B-frag loads + same
// loop control now feed 16 MFMAs; tap-iterations halve chip-wide (512
// blocks). Window 18x22xWS68 = 53,856B (same 4sd margins, same bank
// rotation); epilogue two-phase (slab 5x9,216B aliases into window).
// (512,2) caps VGPR at 128 = exactly 2 blocks/CU x 4 waves/SIMD.

typedef __attribute__((ext_vector_type(8))) short bf16x8;
typedef __attribute__((ext_vector_type(8))) unsigned short u16x8;
typedef __attribute__((ext_vector_type(4))) float f32x4;
typedef __attribute__((ext_vector_type(2))) float f32x2;

#define WR 18    // window rows: [h0-7, h0+10], 4 px rows + 4sd margins
#define WC 22    // window cols: [w0-7, w0+14], 8 px cols + 4sd margins
#define WS 68    // window position stride in shorts (34 dwords -> +2 bank rotate)
#define SLS2 36  // slab o-stride in floats (32 px + 4 pad)

__device__ __forceinline__ unsigned short f2bf(float f) {
    __hip_bfloat16 h = __float2bfloat16(f);
    return *reinterpret_cast<unsigned short*>(&h);
}
__device__ __forceinline__ f32x2 unpk(unsigned u) {
    f32x2 r;
    r[0] = __uint_as_float(u << 16);
    r[1] = __uint_as_float(u & 0xffff0000u);
    return r;
}

// Merged prep: blocks [0,256): x[b][c][h][w] f32 -> xTb[b][h][w][c] bf16;
// blocks [256,1584): f[o][c][k] f32 -> wpF in MFMA-fragment order:
//   wpF[k][ct][cg][lane][j] = f[o=ct*16+(lane&15)][c=cg*32+(lane>>4)*8+j][k]
__global__ __launch_bounds__(256) void k_prep(
    const float* __restrict__ x,
    const float* __restrict__ f1, const float* __restrict__ f2, const float* __restrict__ f3,
    unsigned short* __restrict__ xTb,
    unsigned short* __restrict__ wp1, unsigned short* __restrict__ wp2, unsigned short* __restrict__ wp3) {
    __shared__ float tile[64][65];
    int bid = blockIdx.x;
    int tid = threadIdx.x;
    if (bid < 256) {
        int b = bid >> 6, h = bid & 63;
        {
            int w = tid & 63, c4 = tid >> 6;
            const float* xp = x + (((b * 64) * 64 + h) * 64) + w;
            #pragma unroll
            for (int i = 0; i < 16; ++i) {
                int c = c4 * 16 + i;
                tile[c][w] = xp[c * 4096];
            }
        }
        __syncthreads();
        {
            int c = tid & 63, w4 = tid >> 6;
            unsigned short* op = xTb + (((b * 64 + h) * 64) * 64) + c;
            #pragma unroll
            for (int i = 0; i < 16; ++i) {
                int ww = w4 * 16 + i;
                op[ww * 64] = f2bf(tile[c][ww]);
            }
        }
    } else {
        int idx = (bid - 256) * 256 + tid;      // 83*4096 = 339968 total
        const float* f; unsigned short* wp; int K, rel;
        if (idx < 36864)       { f = f1; wp = wp1; K = 9;  rel = idx; }
        else if (idx < 139264) { f = f2; wp = wp2; K = 25; rel = idx - 36864; }
        else                   { f = f3; wp = wp3; K = 49; rel = idx - 139264; }
        int k    = rel >> 12;
        int r2   = rel & 4095;
        int ct   = r2 >> 10;
        int cg   = (r2 >> 9) & 1;
        int lane = (r2 >> 3) & 63;
        int j    = r2 & 7;
        int o = ct * 16 + (lane & 15);
        int c = cg * 32 + (lane >> 4) * 8 + j;
        wp[rel] = f2bf(f[(o * 64 + c) * K + k]);
    }
}

// One pixel-set: weights, oow + window gathers (rare global fixup), pack.
// Produces A0##S, A1##S (declared by caller).
#define PIXSET(S, ph_, pw_, dy_, dx_, mk_)                                    \
    {                                                                         \
        float py = (float)((ph_) - pad + ky) + (dy_);                         \
        float px = (float)((pw_) - pad + kx) + (dx_);                         \
        float y0f = floorf(py), x0f = floorf(px);                             \
        float wy = py - y0f, wx = px - x0f;                                   \
        int y0 = (int)y0f, x0 = (int)x0f;                                     \
        int y1 = y0 + 1, x1 = x0 + 1;                                         \
        float fy0 = ((unsigned)y0 < 64u) ? (1.f - wy) * (mk_) : 0.f;          \
        float fy1 = ((unsigned)y1 < 64u) ? wy * (mk_)         : 0.f;          \
        float gx0 = ((unsigned)x0 < 64u) ? (1.f - wx)         : 0.f;          \
        float gx1 = ((unsigned)x1 < 64u) ? wx                 : 0.f;          \
        float w00 = fy0 * gx0, w01 = fy0 * gx1;                               \
        float w10 = fy1 * gx0, w11 = fy1 * gx1;                               \
        int r0 = y0 - ylo, r1 = r0 + 1;                                       \
        int c0 = x0 - cxlo, c1 = c0 + 1;                                      \
        bool oow = ((w00 != 0.f) & (((unsigned)r0 >= WR) | ((unsigned)c0 >= WC)))  \
                 | ((w01 != 0.f) & (((unsigned)r0 >= WR) | ((unsigned)c1 >= WC)))  \
                 | ((w10 != 0.f) & (((unsigned)r1 >= WR) | ((unsigned)c0 >= WC)))  \
                 | ((w11 != 0.f) & (((unsigned)r1 >= WR) | ((unsigned)c1 >= WC))); \
        int r0c = min(max(r0, 0), WR - 1), r1c = min(max(r1, 0), WR - 1);     \
        int c0c = min(max(c0, 0), WC - 1), c1c = min(max(c1, 0), WC - 1);     \
        int p00 = (r0c * WC + c0c) * WS;                                      \
        int p01 = (r0c * WC + c1c) * WS;                                      \
        int p10 = (r1c * WC + c0c) * WS;                                      \
        int p11 = (r1c * WC + c1c) * WS;                                      \
        union U { u16x8 v; unsigned u[4]; };                                  \
        U g00a, g01a, g10a, g11a, g00b, g01b, g10b, g11b;                     \
        g00a.v = *(const u16x8*)(win + p00 + ch0);                            \
        g01a.v = *(const u16x8*)(win + p01 + ch0);                            \
        g10a.v = *(const u16x8*)(win + p10 + ch0);                            \
        g11a.v = *(const u16x8*)(win + p11 + ch0);                            \
        g00b.v = *(const u16x8*)(win + p00 + 32 + ch0);                       \
        g01b.v = *(const u16x8*)(win + p01 + 32 + ch0);                       \
        g10b.v = *(const u16x8*)(win + p10 + 32 + ch0);                       \
        g11b.v = *(const u16x8*)(win + p11 + 32 + ch0);                       \
        if (oow) {                                                            \
            int y0g = min(max(y0, 0), 63), y1g = min(max(y1, 0), 63);         \
            int x0g = min(max(x0, 0), 63), x1g = min(max(x1, 0), 63);         \
            int o00 = ((y0g << 6) + x0g) << 6;                                \
            int o01 = ((y0g << 6) + x1g) << 6;                                \
            int o10 = ((y1g << 6) + x0g) << 6;                                \
            int o11 = ((y1g << 6) + x1g) << 6;                                \
            g00a.v = *(const u16x8*)(xb + o00 + ch0);                         \
            g01a.v = *(const u16x8*)(xb + o01 + ch0);                         \
            g10a.v = *(const u16x8*)(xb + o10 + ch0);                         \
            g11a.v = *(const u16x8*)(xb + o11 + ch0);                         \
            g00b.v = *(const u16x8*)(xb + o00 + 32 + ch0);                    \
            g01b.v = *(const u16x8*)(xb + o01 + 32 + ch0);                    \
            g10b.v = *(const u16x8*)(xb + o10 + 32 + ch0);                    \
            g11b.v = *(const u16x8*)(xb + o11 + 32 + ch0);                    \
        }                                                                     \
        f32x2 W00 = {w00, w00}, W01 = {w01, w01};                             \
        f32x2 W10 = {w10, w10}, W11 = {w11, w11};                             \
        _Pragma("unroll")                                                     \
        for (int j2 = 0; j2 < 4; ++j2) {                                      \
            f32x2 s0 = W00 * unpk(g00a.u[j2]) + W01 * unpk(g01a.u[j2])        \
                     + W10 * unpk(g10a.u[j2]) + W11 * unpk(g11a.u[j2]);       \
            f32x2 s1 = W00 * unpk(g00b.u[j2]) + W01 * unpk(g01b.u[j2])        \
                     + W10 * unpk(g10b.u[j2]) + W11 * unpk(g11b.u[j2]);       \
            A0##S.u[2 * j2]     = f2bf(s0[0]);                                \
            A0##S.u[2 * j2 + 1] = f2bf(s0[1]);                                \
            A1##S.u[2 * j2]     = f2bf(s1[0]);                                \
            A1##S.u[2 * j2 + 1] = f2bf(s1[1]);                                \
        }                                                                     \
    }

__global__ __launch_bounds__(512, 2) void k_dcn(
    const unsigned short* __restrict__ xTb,
    const float* __restrict__ off1, const float* __restrict__ msk1, const unsigned short* __restrict__ wp1,
    const float* __restrict__ off2, const float* __restrict__ msk2, const unsigned short* __restrict__ wp2,
    const float* __restrict__ off3, const float* __restrict__ msk3, const unsigned short* __restrict__ wp3,
    float* __restrict__ out) {

    __shared__ __align__(16) unsigned char smem[WR * WC * WS * 2];   // 53,856 B
    unsigned short* win = (unsigned short*)smem;
    float* slab = (float*)smem;          // aliased in epilogue (5*9216 = 46,080 B)

    int tile = blockIdx.x;               // 0..511
    int b  = tile >> 7;
    int h0 = ((tile >> 3) & 15) << 2;    // 4-row tile
    int w0 = (tile & 7) << 3;            // 8-col tile

    int tid  = threadIdx.x;
    int wv   = tid >> 6;                 // 0..7
    int lane = tid & 63;
    int quad = lane >> 4;
    int l16  = lane & 15;
    int ylo  = h0 - 7, cxlo = w0 - 7;

    const unsigned short* xb = xTb + ((size_t)b << 18);

    // two pixels per l16: set A = px id l16 (rows 0-1), set B = px id 16+l16
    int phA = h0 + (l16 >> 3),     pwA = w0 + (l16 & 7);
    int phB = h0 + 2 + (l16 >> 3), pwB = w0 + (l16 & 7);
    int ch0  = quad << 3;
    int lofs = lane << 3;                // lane*8 shorts = lane*16 B

    // ---- per-wave descriptor: 8 single tap-ranges (same split) ----
    const float* offs; const float* msks; const unsigned short* wpF;
    int ks, ke, kw, pad;
    switch (wv) {
        case 0:  offs = off1; msks = msk1; wpF = wp1; kw = 3; pad = 1; ks = 0;  ke = 9;  break;
        case 1:  offs = off2; msks = msk2; wpF = wp2; kw = 5; pad = 2; ks = 0;  ke = 12; break;
        case 2:  offs = off2; msks = msk2; wpF = wp2; kw = 5; pad = 2; ks = 12; ke = 25; break;
        case 3:  offs = off3; msks = msk3; wpF = wp3; kw = 7; pad = 3; ks = 0;  ke = 10; break;
        case 4:  offs = off3; msks = msk3; wpF = wp3; kw = 7; pad = 3; ks = 10; ke = 20; break;
        case 5:  offs = off3; msks = msk3; wpF = wp3; kw = 7; pad = 3; ks = 20; ke = 30; break;
        case 6:  offs = off3; msks = msk3; wpF = wp3; kw = 7; pad = 3; ks = 30; ke = 40; break;
        default: offs = off3; msks = msk3; wpF = wp3; kw = 7; pad = 3; ks = 40; ke = 49; break;
    }
    int K2 = (kw == 3) ? 9 : (kw == 5) ? 25 : 49;
    const float* offpA = offs + ((b * 2 * K2) * 4096) + (phA << 6) + pwA;
    const float* mskpA = msks + ((b * K2) * 4096) + (phA << 6) + pwA;
    const float* offpB = offs + ((b * 2 * K2) * 4096) + (phB << 6) + pwB;
    const float* mskpB = msks + ((b * K2) * 4096) + (phB << 6) + pwB;

    // ---- param preload for k=ks (distance 1), before staging ----
    float dyCa = offpA[ks * 8192], dxCa = offpA[ks * 8192 + 4096], mkCa = mskpA[ks * 4096];
    float dyCb = offpB[ks * 8192], dxCb = offpB[ks * 8192 + 4096], mkCb = mskpB[ks * 4096];

    // ---- stage window: 396 positions x 128 B, coalesced, 512 threads ----
    {
        int j = tid & 7;
        for (int p = tid >> 3; p < WR * WC; p += 64) {
            int r = p / WC, cc = p - r * WC;
            int y = min(max(ylo + r, 0), 63);
            int x = min(max(cxlo + cc, 0), 63);
            *(u16x8*)(win + p * WS + j * 8) =
                *(const u16x8*)(xb + (((y << 6) + x) << 6) + j * 8);
        }
    }
    __syncthreads();

    f32x4 accA[4], accB[4];
    #pragma unroll
    for (int i = 0; i < 4; ++i) {
        accA[i] = (f32x4){0.f, 0.f, 0.f, 0.f};
        accB[i] = (f32x4){0.f, 0.f, 0.f, 0.f};
    }

    int ky = ks / kw, kx = ks - ky * kw;

    for (int k = ks; k < ke; ++k) {
        // B fragments for THIS tap (shared by both pixel sets -> 2x reuse)
        const unsigned short* wpk = wpF + (k << 12) + lofs;
        bf16x8 b00 = *(const bf16x8*)(wpk);
        bf16x8 b01 = *(const bf16x8*)(wpk + 512);
        bf16x8 b10 = *(const bf16x8*)(wpk + 1024);
        bf16x8 b11 = *(const bf16x8*)(wpk + 1536);
        bf16x8 b20 = *(const bf16x8*)(wpk + 2048);
        bf16x8 b21 = *(const bf16x8*)(wpk + 2560);
        bf16x8 b30 = *(const bf16x8*)(wpk + 3072);
        bf16x8 b31 = *(const bf16x8*)(wpk + 3584);

        // param prefetch for tap k+1 (both sets)
        int kn = min(k + 1, ke - 1);
        float dyNa = offpA[kn * 8192], dxNa = offpA[kn * 8192 + 4096], mkNa = mskpA[kn * 4096];
        float dyNb = offpB[kn * 8192], dxNb = offpB[kn * 8192 + 4096], mkNb = mskpB[kn * 4096];

        union { bf16x8 v; unsigned short u[8]; } A0a, A1a, A0b, A1b;
        PIXSET(a, phA, pwA, dyCa, dxCa, mkCa)
        PIXSET(b, phB, pwB, dyCb, dxCb, mkCb)

        accA[0] = __builtin_amdgcn_mfma_f32_16x16x32_bf16(A0a.v, b00, accA[0], 0, 0, 0);
        accA[0] = __builtin_amdgcn_mfma_f32_16x16x32_bf16(A1a.v, b01, accA[0], 0, 0, 0);
        accA[1] = __builtin_amdgcn_mfma_f32_16x16x32_bf16(A0a.v, b10, accA[1], 0, 0, 0);
        accA[1] = __builtin_amdgcn_mfma_f32_16x16x32_bf16(A1a.v, b11, accA[1], 0, 0, 0);
        accA[2] = __builtin_amdgcn_mfma_f32_16x16x32_bf16(A0a.v, b20, accA[2], 0, 0, 0);
        accA[2] = __builtin_amdgcn_mfma_f32_16x16x32_bf16(A1a.v, b21, accA[2], 0, 0, 0);
        accA[3] = __builtin_amdgcn_mfma_f32_16x16x32_bf16(A0a.v, b30, accA[3], 0, 0, 0);
        accA[3] = __builtin_amdgcn_mfma_f32_16x16x32_bf16(A1a.v, b31, accA[3], 0, 0, 0);
        accB[0] = __builtin_amdgcn_mfma_f32_16x16x32_bf16(A0b.v, b00, accB[0], 0, 0, 0);
        accB[0] = __builtin_amdgcn_mfma_f32_16x16x32_bf16(A1b.v, b01, accB[0], 0, 0, 0);
        accB[1] = __builtin_amdgcn_mfma_f32_16x16x32_bf16(A0b.v, b10, accB[1], 0, 0, 0);
        accB[1] = __builtin_amdgcn_mfma_f32_16x16x32_bf16(A1b.v, b11, accB[1], 0, 0, 0);
        accB[2] = __builtin_amdgcn_mfma_f32_16x16x32_bf16(A0b.v, b20, accB[2], 0, 0, 0);
        accB[2] = __builtin_amdgcn_mfma_f32_16x16x32_bf16(A1b.v, b21, accB[2], 0, 0, 0);
        accB[3] = __builtin_amdgcn_mfma_f32_16x16x32_bf16(A0b.v, b30, accB[3], 0, 0, 0);
        accB[3] = __builtin_amdgcn_mfma_f32_16x16x32_bf16(A1b.v, b31, accB[3], 0, 0, 0);

        dyCa = dyNa; dxCa = dxNa; mkCa = mkNa;
        dyCb = dyNb; dxCb = dxNb; mkCb = mkNb;
        if (++kx == kw) { kx = 0; ++ky; }
    }

    __syncthreads();    // all waves done reading window; safe to alias as slab

    // ---- epilogue phase A: br0 (wv0) + br1 (wv1,2) -> slabs 0..2 ----
    if (wv < 3) {
        #pragma unroll
        for (int ct = 0; ct < 4; ++ct) {
            *(f32x4*)&slab[wv * 2304 + (ct * 16 + l16) * SLS2 + quad * 4]      = accA[ct];
            *(f32x4*)&slab[wv * 2304 + (ct * 16 + l16) * SLS2 + 16 + quad * 4] = accB[ct];
        }
    }
    __syncthreads();
    // store o in [0,128): 128 o x 8 px-groups (grp -> row=grp>>1, col=(grp&1)*4)
    for (int it = tid; it < 1024; it += 512) {
        int o = it >> 3, grp = it & 7;
        int base = (o & 63) * SLS2 + grp * 4;
        f32x4 v;
        if (o < 64) {
            v = *(const f32x4*)&slab[base];
        } else {
            f32x4 a0 = *(const f32x4*)&slab[1 * 2304 + base];
            f32x4 a1 = *(const f32x4*)&slab[2 * 2304 + base];
            #pragma unroll
            for (int r = 0; r < 4; ++r) v[r] = a0[r] + a1[r];
        }
        *(f32x4*)&out[(((size_t)b * 192 + o) * 64 + h0 + (grp >> 1)) * 64 + w0 + (grp & 1) * 4] = v;
    }
    __syncthreads();    // phase-A reads done before phase-B overwrites

    // ---- epilogue phase B: br2 (wv3..7) -> slabs 0..4 ----
    if (wv >= 3) {
        #pragma unroll
        for (int ct = 0; ct < 4; ++ct) {
            *(f32x4*)&slab[(wv - 3) * 2304 + (ct * 16 + l16) * SLS2 + quad * 4]      = accA[ct];
            *(f32x4*)&slab[(wv - 3) * 2304 + (ct * 16 + l16) * SLS2 + 16 + quad * 4] = accB[ct];
        }
    }
    __syncthreads();
    // store o in [128,192): 64 o x 8 groups = 512 items, 1/thread
    {
        int it = tid;
        int oo = it >> 3, grp = it & 7;
        int base = oo * SLS2 + grp * 4;
        f32x4 a0 = *(const f32x4*)&slab[0 * 2304 + base];
        f32x4 a1 = *(const f32x4*)&slab[1 * 2304 + base];
        f32x4 a2 = *(const f32x4*)&slab[2 * 2304 + base];
        f32x4 a3 = *(const f32x4*)&slab[3 * 2304 + base];
        f32x4 a4 = *(const f32x4*)&slab[4 * 2304 + base];
        f32x4 v;
        #pragma unroll
        for (int r = 0; r < 4; ++r) v[r] = (a0[r] + a1[r]) + (a2[r] + a3[r]) + a4[r];
        *(f32x4*)&out[(((size_t)b * 192 + 128 + oo) * 64 + h0 + (grp >> 1)) * 64 + w0 + (grp & 1) * 4] = v;
    }
}

extern "C" void kernel_launch(void* const* d_in, const int* in_sizes, int n_in,
                              void* d_out, int out_size, void* d_ws, size_t ws_size,
                              hipStream_t stream) {
    const float* x    = (const float*)d_in[0];
    const float* f1   = (const float*)d_in[1];
    const float* off1 = (const float*)d_in[2];
    const float* msk1 = (const float*)d_in[3];
    const float* f2   = (const float*)d_in[4];
    const float* off2 = (const float*)d_in[5];
    const float* msk2 = (const float*)d_in[6];
    const float* f3   = (const float*)d_in[7];
    const float* off3 = (const float*)d_in[8];
    const float* msk3 = (const float*)d_in[9];
    float* out = (float*)d_out;

    // ws: xTb 2MB bf16 | wpF1/wpF2/wpF3 bf16 (fragment-major)
    unsigned short* xTb = (unsigned short*)d_ws;
    unsigned short* wp1 = xTb + 4 * 64 * 64 * 64;
    unsigned short* wp2 = wp1 + 9 * 4096;
    unsigned short* wp3 = wp2 + 25 * 4096;

    k_prep<<<dim3(1584), dim3(256), 0, stream>>>(x, f1, f2, f3, xTb, wp1, wp2, wp3);
    k_dcn<<<dim3(512), dim3(512), 0, stream>>>(xTb,
                                               off1, msk1, wp1,
                                               off2, msk2, wp2,
                                               off3, msk3, wp3,
                                               out);
}